// Round 3
// baseline (925.509 us; speedup 1.0000x reference)
//
#include <hip/hip_runtime.h>
#include <hip/hip_bf16.h>

// Problem constants
#define BB 32
#define NNODE 512
#define EE 128
#define MAXDEG 64  // fixed edge slots per row (binomial(512,.05) max ~53)

typedef float v2f __attribute__((ext_vector_type(2)));
__device__ __forceinline__ v2f fma2(v2f a, v2f b, v2f c) {
  return __builtin_elementwise_fma(a, b, c);
}

// Fast gates: v_rcp_f32 instead of full-precision divide (~1ulp).
__device__ __forceinline__ float sigm_fast(float x) {
  return __builtin_amdgcn_rcpf(1.0f + __expf(-x));
}
__device__ __forceinline__ float tanh_fast(float x) {
  x = fminf(20.f, fmaxf(-20.f, x));
  float t = __expf(-2.f * x);
  return (1.f - t) * __builtin_amdgcn_rcpf(1.f + t);
}

// ---------------------------------------------------------------------------
// wh[2s|2s+1][:, 0:64] = relu(LIT @ W_lit); xp = SEM @ gru_k + gru_b[0]
// grid 1024 x 64.
__global__ __launch_bounds__(64, 1) void k_data(
    const float* __restrict__ lit1, const float* __restrict__ sem1,
    const float* __restrict__ lit2, const float* __restrict__ sem2,
    const float* __restrict__ wl1, const float* __restrict__ gk1,
    const float* __restrict__ gb1, const float* __restrict__ wl2,
    const float* __restrict__ gk2, const float* __restrict__ gb2,
    float* __restrict__ wh, float* __restrict__ xp) {
  __shared__ float stage[64 * 65];
  int bid = blockIdx.x;
  int rowblk = bid >> 1, half = bid & 1;
  int grow0 = rowblk * 64;
  int side = grow0 >> 14;
  int lrow0 = grow0 & 16383;
  const float* lit = side ? lit2 : lit1;
  const float* sem = side ? sem2 : sem1;
  const float* wl = side ? wl2 : wl1;
  const float* gk = side ? gk2 : gk1;
  const float* gb = side ? gb2 : gb1;
  int tid = threadIdx.x;

  {
    const float4* lit4 = (const float4*)(lit + (size_t)lrow0 * 64);
#pragma unroll
    for (int p = 0; p < 16; ++p) {
      int s = p * 64 + tid;
      int r = s >> 4, q = s & 15;
      float4 v = lit4[r * 16 + q];
      stage[r * 65 + 4 * q + 0] = v.x;
      stage[r * 65 + 4 * q + 1] = v.y;
      stage[r * 65 + 4 * q + 2] = v.z;
      stage[r * 65 + 4 * q + 3] = v.w;
    }
    v2f acc[16];
#pragma unroll
    for (int c = 0; c < 16; ++c) acc[c] = (v2f){0.f, 0.f};
    const float4* wl4 = (const float4*)wl;  // [64][16] f4
    for (int i = 0; i < 64; ++i) {
      float rv = stage[tid * 65 + i];
      v2f rv2 = {rv, rv};
#pragma unroll
      for (int c4 = 0; c4 < 8; ++c4) {
        float4 w = wl4[i * 16 + half * 8 + c4];
        acc[2 * c4 + 0] = fma2(rv2, (v2f){w.x, w.y}, acc[2 * c4 + 0]);
        acc[2 * c4 + 1] = fma2(rv2, (v2f){w.z, w.w}, acc[2 * c4 + 1]);
      }
    }
    float4* w0 = (float4*)wh + ((size_t)(2 * side) * 16384 + lrow0 + tid) * 32;
    float4* w1 =
        (float4*)wh + ((size_t)(2 * side + 1) * 16384 + lrow0 + tid) * 32;
#pragma unroll
    for (int c4 = 0; c4 < 8; ++c4) {
      float4 o;
      o.x = fmaxf(acc[2 * c4].x, 0.f);
      o.y = fmaxf(acc[2 * c4].y, 0.f);
      o.z = fmaxf(acc[2 * c4 + 1].x, 0.f);
      o.w = fmaxf(acc[2 * c4 + 1].y, 0.f);
      w0[half * 8 + c4] = o;
      w1[half * 8 + c4] = o;
    }
  }
  {
    const float4* sem4 = (const float4*)(sem + (size_t)lrow0 * 64);
#pragma unroll
    for (int p = 0; p < 16; ++p) {
      int s = p * 64 + tid;
      int r = s >> 4, q = s & 15;
      float4 v = sem4[r * 16 + q];
      stage[r * 65 + 4 * q + 0] = v.x;
      stage[r * 65 + 4 * q + 1] = v.y;
      stage[r * 65 + 4 * q + 2] = v.z;
      stage[r * 65 + 4 * q + 3] = v.w;
    }
    v2f acc2[48];
#pragma unroll
    for (int c = 0; c < 48; ++c)
      acc2[c] = (v2f){gb[half * 96 + 2 * c], gb[half * 96 + 2 * c + 1]};
    const float4* gk4 = (const float4*)gk;  // [64][48] f4
    for (int i = 0; i < 64; ++i) {
      float rv = stage[tid * 65 + i];
      v2f rv2 = {rv, rv};
#pragma unroll
      for (int c4 = 0; c4 < 24; ++c4) {
        float4 w = gk4[i * 48 + half * 24 + c4];
        acc2[2 * c4 + 0] = fma2(rv2, (v2f){w.x, w.y}, acc2[2 * c4 + 0]);
        acc2[2 * c4 + 1] = fma2(rv2, (v2f){w.z, w.w}, acc2[2 * c4 + 1]);
      }
    }
    float4* xp4 = (float4*)xp;
    int grow = grow0 + tid;
#pragma unroll
    for (int c4 = 0; c4 < 24; ++c4) {
      float4 o;
      o.x = acc2[2 * c4].x;
      o.y = acc2[2 * c4].y;
      o.z = acc2[2 * c4 + 1].x;
      o.w = acc2[2 * c4 + 1].y;
      xp4[(size_t)grow * 48 + half * 24 + c4] = o;
    }
  }
}

// ---------------------------------------------------------------------------
// CSR/CSC build (standalone so the GRU kernel gets a full register budget).
// grid 1024 x 256.
__global__ __launch_bounds__(256, 1) void k_csr(
    const float* __restrict__ A1, const float* __restrict__ A2,
    int* __restrict__ counts, int* __restrict__ edges) {
  int bid = blockIdx.x;
  int t = threadIdx.x;
  if (bid < 512) {
    int s = bid >> 8, b = (bid >> 3) & 31, ch = bid & 7;
    const float* A = s ? A2 : A1;
    const float4* A4 = (const float4*)(A + ((size_t)b * 512 + ch * 64) * 512);
    __shared__ int crow[64];
    if (t < 64) crow[t] = 0;
    __syncthreads();
    int* efwd =
        edges + (size_t)(2 * s) * 1048576 + ((size_t)b * 512 + ch * 64) * 64;
#pragma unroll
    for (int it = 0; it < 32; ++it) {
      int idx = it * 256 + t;
      int r = idx >> 7, c4 = idx & 127;
      float4 v = A4[idx];
      float vv[4] = {v.x, v.y, v.z, v.w};
#pragma unroll
      for (int e = 0; e < 4; ++e) {
        if (vv[e] != 0.f) {
          int pos = atomicAdd(&crow[r], 1);
          if (pos < MAXDEG) efwd[r * 64 + pos] = 4 * c4 + e;
        }
      }
    }
    __syncthreads();
    if (t < 64)
      counts[(2 * s) * 16384 + b * 512 + ch * 64 + t] = min(crow[t], MAXDEG);
  } else {
    int bid2 = bid - 512;
    int s = bid2 >> 8, b = (bid2 >> 3) & 31, cch = bid2 & 7;
    const float* A = s ? A2 : A1;
    __shared__ int ccol[64];
    if (t < 64) ccol[t] = 0;
    __syncthreads();
    int lane = t & 63, rg = t >> 6;
    int c = cch * 64 + lane;
    int* erev = edges + (size_t)(2 * s + 1) * 1048576 + ((size_t)b * 512) * 64;
    const float* Ab = A + (size_t)b * 512 * 512;
    for (int it = 0; it < 128; ++it) {
      int r = it * 4 + rg;
      float a = Ab[(size_t)r * 512 + c];
      if (a != 0.f) {
        int pos = atomicAdd(&ccol[lane], 1);
        if (pos < MAXDEG) erev[(size_t)c * 64 + pos] = r;
      }
    }
    __syncthreads();
    if (t < 64)
      counts[(2 * s + 1) * 16384 + b * 512 + cch * 64 + t] =
          min(ccol[t], MAXDEG);
  }
}

// ---------------------------------------------------------------------------
// GRU scan, SINGLE-WAVE per sequence, dedicated kernel with full VGPR budget.
// Lane jj owns h[jj] and the full 192-float recurrent weight column in VGPRs
// (~280 VGPR live; __launch_bounds__(64,1) allows up to 512 — round-1's spill
// came from the fused 256-thread kernel's low allocation).
// xp is consumed per-lane only -> register double-buffer of 8 steps, all
// statically indexed; LDS holds only the 64-float h broadcast.
// No barriers, no shfl: single-wave lockstep + in-order DS pipe; a
// sched_barrier(0) pins the hs write after the h-reads of the same step.
// grid 64 x 64.
__global__ __launch_bounds__(64, 1) void k_gru(
    const float* __restrict__ xp, const float* __restrict__ rk1,
    const float* __restrict__ b1, const float* __restrict__ rk2,
    const float* __restrict__ b2, float* __restrict__ wh) {
  int blk = blockIdx.x;
  int side = blk >> 5, b = blk & 31;
  int jj = threadIdx.x;  // output index 0..63
  const float* rk = side ? rk2 : rk1;
  const float* bbp = side ? b2 : b1;
  // Full recurrent weight column for this lane: 96 v2f = 192 VGPRs.
  v2f wz[32], wr[32], wv[32];
#pragma unroll
  for (int p = 0; p < 32; ++p) {
    const float* r0 = rk + (size_t)(2 * p) * 192 + jj;
    const float* r1 = r0 + 192;
    wz[p] = (v2f){r0[0], r1[0]};
    wr[p] = (v2f){r0[64], r1[64]};
    wv[p] = (v2f){r0[128], r1[128]};
  }
  float bz = bbp[192 + jj], brr = bbp[192 + 64 + jj], bv = bbp[192 + 128 + jj];

  __shared__ float hs[64];
  hs[jj] = 0.f;
  float hold = 0.f;

  const float* xpr = xp + (size_t)(side * 16384 + b * 512) * 192;
  float* w0 = wh + ((size_t)(2 * side) * 16384 + b * 512) * 128 + 64 + jj;
  float* w1 = wh + ((size_t)(2 * side + 1) * 16384 + b * 512) * 128 + 64 + jj;

  float bufA[24], bufB[24];
  // load 8-step chunk tc into buf (per-lane scalars, coalesced 256B/instr)
  auto loadc = [&](float (&buf)[24], int tc) {
    const float* src = xpr + (size_t)tc * 8 * 192;
#pragma unroll
    for (int q = 0; q < 8; ++q) {
      buf[3 * q + 0] = src[q * 192 + jj];
      buf[3 * q + 1] = src[q * 192 + 64 + jj];
      buf[3 * q + 2] = src[q * 192 + 128 + jj];
    }
  };
  // one GRU step from buf[tt], global step index t
  auto gstep = [&](const float (&buf)[24], int tt, int t) {
    float cxz = buf[3 * tt + 0], cxr = buf[3 * tt + 1], cxv = buf[3 * tt + 2];
    const float4* h4 = (const float4*)hs;  // broadcast reads (conflict-free)
    v2f az = {0.f, 0.f}, ar = {0.f, 0.f}, av = {0.f, 0.f};
#pragma unroll
    for (int c = 0; c < 16; ++c) {
      float4 h = h4[c];
      v2f hlo = {h.x, h.y}, hhi = {h.z, h.w};
      az = fma2(hlo, wz[2 * c], az);
      az = fma2(hhi, wz[2 * c + 1], az);
      ar = fma2(hlo, wr[2 * c], ar);
      ar = fma2(hhi, wr[2 * c + 1], ar);
      av = fma2(hlo, wv[2 * c], av);
      av = fma2(hhi, wv[2 * c + 1], av);
    }
    float saz = az.x + az.y, sar = ar.x + ar.y, sav = av.x + av.y;
    float z = sigm_fast(cxz + saz + bz);
    float r = sigm_fast(cxr + sar + brr);
    float hh = tanh_fast(cxv + r * (sav + bv));
    float hnew = fmaf(z, hold - hh, hh);
    hold = hnew;
    // Pin schedule: all hs reads of this step must be issued before the
    // write below (data-dep usually enforces this; fence makes it explicit).
    __builtin_amdgcn_sched_barrier(0);
    hs[jj] = hnew;
    float rv = fmaxf(hnew, 0.f);
    w0[(size_t)t * 128] = rv;
    w1[(size_t)t * 128] = rv;
  };

  loadc(bufA, 0);
  for (int tc2 = 0; tc2 < 32; ++tc2) {  // 64 chunks of 8 steps, paired A/B
    int tcA = 2 * tc2, tcB = 2 * tc2 + 1;
    loadc(bufB, tcB);  // prefetch while computing A
#pragma unroll
    for (int tt = 0; tt < 8; ++tt) gstep(bufA, tt, tcA * 8 + tt);
    if (tcB + 1 < 64) loadc(bufA, tcB + 1);  // prefetch while computing B
#pragma unroll
    for (int tt = 0; tt < 8; ++tt) gstep(bufB, tt, tcB * 8 + tt);
  }
}

// ---------------------------------------------------------------------------
// whg (PACKED BF16: uint = 2 cols) = wh @ W_g; ah1/ah2 fp32.
// grid 1024 x 64; one wave = 64 rows. XCD-swizzled (blockIdx%8 = XCD): all 8
// blocks of one (st,b) group land on the same XCD so whg stays in its L2.
__global__ __launch_bounds__(64, 1) void k_whg(
    const float* __restrict__ wh, const float* __restrict__ Wg,
    const float* __restrict__ a1w, const float* __restrict__ a1b,
    const float* __restrict__ a2w, const float* __restrict__ a2b,
    unsigned int* __restrict__ whg, float* __restrict__ ah1,
    float* __restrict__ ah2) {
  __shared__ float stage[64 * 129];
  int B = blockIdx.x;
  int xcd = B & 7, slot = B >> 3;   // slot 0..127
  int grp = xcd + 8 * (slot >> 3);  // (st,b) group 0..127
  int sub = slot & 7;               // 64-row tile within group
  int rowbase = grp * 512 + sub * 64;
  int tid = threadIdx.x;
  const float4* wh4 = (const float4*)(wh + (size_t)rowbase * 128);
#pragma unroll
  for (int p = 0; p < 32; ++p) {
    int s = p * 64 + tid;
    int r = s >> 5, q = s & 31;
    float4 v = wh4[r * 32 + q];
    stage[r * 129 + 4 * q + 0] = v.x;
    stage[r * 129 + 4 * q + 1] = v.y;
    stage[r * 129 + 4 * q + 2] = v.z;
    stage[r * 129 + 4 * q + 3] = v.w;
  }
  v2f acc[64];
#pragma unroll
  for (int c = 0; c < 64; ++c) acc[c] = (v2f){0.f, 0.f};
  float p1 = a1b[0], p2 = a2b[0];
  const float4* Wg4 = (const float4*)Wg;  // [128][32] f4
  for (int i = 0; i < 128; ++i) {
    float rv = stage[tid * 129 + i];
    v2f rv2 = {rv, rv};
    p1 = fmaf(rv, a1w[i], p1);
    p2 = fmaf(rv, a2w[i], p2);
#pragma unroll
    for (int c4 = 0; c4 < 32; ++c4) {
      float4 w = Wg4[i * 32 + c4];
      acc[2 * c4 + 0] = fma2(rv2, (v2f){w.x, w.y}, acc[2 * c4 + 0]);
      acc[2 * c4 + 1] = fma2(rv2, (v2f){w.z, w.w}, acc[2 * c4 + 1]);
    }
  }
  int grow = rowbase + tid;
  uint2* o2 = (uint2*)(whg + (size_t)grow * 64);
#pragma unroll
  for (int c4 = 0; c4 < 32; c4 += 2) {
    __hip_bfloat162 A =
        __float22bfloat162_rn(make_float2(acc[c4].x, acc[c4].y));
    __hip_bfloat162 Bv =
        __float22bfloat162_rn(make_float2(acc[c4 + 1].x, acc[c4 + 1].y));
    uint2 pk;
    pk.x = *(unsigned int*)&A;
    pk.y = *(unsigned int*)&Bv;
    o2[c4 >> 1] = pk;
  }
  ah1[grow] = p1;
  ah2[grow] = p2;
}

// ---------------------------------------------------------------------------
// Per-row edge softmax + aggregate + elu. One wave per row, 4 rows per block.
// Lane-parallel setup; shfl-broadcast gather; whg is PACKED BF16 so each lane
// reads ONE 4B uint (2 cols) per edge — half the loads/bytes of fp32.
// XCD-swizzled to match k_whg. grid 16384 x 256.
__global__ __launch_bounds__(256, 1) void k_attn(
    float* __restrict__ wh, const unsigned int* __restrict__ whg,
    const float* __restrict__ ah1, const float* __restrict__ ah2,
    const int* __restrict__ counts, const int* __restrict__ edges) {
  int B = blockIdx.x;
  int xcd = B & 7, slot = B >> 3;   // slot 0..2047
  int grp = xcd + 8 * (slot >> 7);  // group 0..127
  int sub = slot & 127;             // 0..127 (4 rows each)
  int row = grp * 512 + sub * 4 + (threadIdx.x >> 6);
  int lane = threadIdx.x & 63;
  int st = row >> 14;
  int loc = row & 16383;
  int base = row & ~511;
  int cnt = counts[row];
  const int* ed = edges + (size_t)st * 1048576 + (size_t)loc * 64;
  int jk = lane < cnt ? ed[lane] : 0;
  float a1v = ah1[row];
  float e = a1v + ah2[base + jk];
  e = e >= 0.f ? e : 0.2f * e;  // leaky_relu 0.2
  float w = lane < cnt ? __expf(e) : 0.f;
  float lsum = w;
#pragma unroll
  for (int off = 32; off; off >>= 1) lsum += __shfl_xor(lsum, off, 64);
  float inv = cnt > 0 ? 1.0f / lsum : 0.f;
  const unsigned int* wgb = whg + (size_t)base * 64;
  v2f a0 = {0.f, 0.f}, a1 = {0.f, 0.f}, a2 = {0.f, 0.f}, a3 = {0.f, 0.f};
  int k = 0;
  for (; k + 4 <= cnt; k += 4) {
    float w0 = __shfl(w, k, 64), w1 = __shfl(w, k + 1, 64);
    float w2 = __shfl(w, k + 2, 64), w3 = __shfl(w, k + 3, 64);
    int j0 = __shfl(jk, k, 64), j1 = __shfl(jk, k + 1, 64);
    int j2 = __shfl(jk, k + 2, 64), j3 = __shfl(jk, k + 3, 64);
    unsigned int d0 = wgb[(size_t)j0 * 64 + lane];
    unsigned int d1 = wgb[(size_t)j1 * 64 + lane];
    unsigned int d2 = wgb[(size_t)j2 * 64 + lane];
    unsigned int d3 = wgb[(size_t)j3 * 64 + lane];
    v2f v0 = {__uint_as_float(d0 << 16), __uint_as_float(d0 & 0xffff0000u)};
    v2f v1 = {__uint_as_float(d1 << 16), __uint_as_float(d1 & 0xffff0000u)};
    v2f v2 = {__uint_as_float(d2 << 16), __uint_as_float(d2 & 0xffff0000u)};
    v2f v3 = {__uint_as_float(d3 << 16), __uint_as_float(d3 & 0xffff0000u)};
    a0 = fma2((v2f){w0, w0}, v0, a0);
    a1 = fma2((v2f){w1, w1}, v1, a1);
    a2 = fma2((v2f){w2, w2}, v2, a2);
    a3 = fma2((v2f){w3, w3}, v3, a3);
  }
  for (; k < cnt; ++k) {
    float w0 = __shfl(w, k, 64);
    int j0 = __shfl(jk, k, 64);
    unsigned int d0 = wgb[(size_t)j0 * 64 + lane];
    v2f v0 = {__uint_as_float(d0 << 16), __uint_as_float(d0 & 0xffff0000u)};
    a0 = fma2((v2f){w0, w0}, v0, a0);
  }
  v2f acc = (a0 + a1) + (a2 + a3);
  // lane covers cols 2*lane, 2*lane+1
  float2* wr2 = (float2*)(wh + (size_t)row * 128);
  float2 old = wr2[lane];
  float o0 = old.x + acc.x * inv;
  float o1 = old.y + acc.y * inv;
  o0 = o0 > 0.f ? o0 : __expf(o0) - 1.f;  // elu
  o1 = o1 > 0.f ? o1 : __expf(o1) - 1.f;
  wr2[lane] = make_float2(o0, o1);
}

// ---------------------------------------------------------------------------
// Fused node-sum + output projection. grid 64 x 256. Block = (side,b).
__global__ __launch_bounds__(256, 1) void k_tail(const float* __restrict__ wh,
                                                 const float* __restrict__ Wout,
                                                 const float* __restrict__ bout,
                                                 float* __restrict__ e12) {
  int sb = blockIdx.x;
  int side = sb >> 5, b = sb & 31;
  int t = threadIdx.x;
  int c = t & 127, half = t >> 7;
  __shared__ float part[2][128];
  __shared__ float mid[128];
  size_t s0 = ((size_t)(2 * side) * 16384 + b * 512) * 128;
  size_t s1 = ((size_t)(2 * side + 1) * 16384 + b * 512) * 128;
  float sum = 0.f;
  int r0 = half * 256;
  for (int r = r0; r < r0 + 256; ++r) {
    sum += wh[s0 + (size_t)r * 128 + c] + wh[s1 + (size_t)r * 128 + c];
  }
  part[half][c] = sum;
  __syncthreads();
  if (t < 128) mid[t] = part[0][t] + part[1][t];
  __syncthreads();
  if (t < 64) {
    float acc = bout[t];
    for (int k2 = 0; k2 < 128; ++k2) acc = fmaf(mid[k2], Wout[k2 * 64 + t], acc);
    e12[sb * 64 + t] = acc;
  }
}

__global__ void k_cos(const float* __restrict__ e12, float* __restrict__ out) {
  int b = threadIdx.x;
  if (b >= 32) return;
  const float* e1 = e12 + b * 64;
  const float* e2 = e12 + 2048 + b * 64;
  float d = 0.f, n1 = 0.f, n2 = 0.f;
  for (int o = 0; o < 64; ++o) {
    float a = e1[o], c = e2[o];
    d = fmaf(a, c, d);
    n1 = fmaf(a, a, n1);
    n2 = fmaf(c, c, n2);
  }
  float nn = fmaxf(sqrtf(n1), 1e-12f) * fmaxf(sqrtf(n2), 1e-12f);
  out[b] = 0.5f * (1.f + d / nn);
}

// ---------------------------------------------------------------------------
extern "C" void kernel_launch(void* const* d_in, const int* in_sizes, int n_in,
                              void* d_out, int out_size, void* d_ws,
                              size_t ws_size, hipStream_t stream) {
  const float* CFG1 = (const float*)d_in[0];
  const float* LIT1 = (const float*)d_in[2];
  const float* SEM1 = (const float*)d_in[3];
  const float* CFG2 = (const float*)d_in[4];
  const float* LIT2 = (const float*)d_in[6];
  const float* SEM2 = (const float*)d_in[7];
  const float* WL1 = (const float*)d_in[8];
  const float* GK1 = (const float*)d_in[9];
  const float* GRK1 = (const float*)d_in[10];
  const float* GB1 = (const float*)d_in[11];
  const float* WL2 = (const float*)d_in[12];
  const float* GK2 = (const float*)d_in[13];
  const float* GRK2 = (const float*)d_in[14];
  const float* GB2 = (const float*)d_in[15];
  const float* A1W = (const float*)d_in[16];
  const float* A1B = (const float*)d_in[17];
  const float* A2W = (const float*)d_in[18];
  const float* A2B = (const float*)d_in[19];
  const float* WG = (const float*)d_in[20];
  const float* WOUT = (const float*)d_in[21];
  const float* BOUT = (const float*)d_in[22];

  float* ws = (float*)d_ws;
  float* wh = ws;            // 8388608 floats
  float* xp = wh + 8388608;  // 6291456
  unsigned int* whg = (unsigned int*)(xp + 6291456);  // 4194304 uints
  float* ah1 = (float*)(whg + 4194304);               // 65536
  float* ah2 = ah1 + 65536;                           // 65536
  float* e12 = ah2 + 65536;                           // 4096
  int* counts = (int*)(e12 + 4096);                   // 65536
  int* edges = counts + 65536;  // 4*16384*64 = 4194304

  k_data<<<1024, 64, 0, stream>>>(LIT1, SEM1, LIT2, SEM2, WL1, GK1, GB1, WL2,
                                  GK2, GB2, wh, xp);
  k_csr<<<1024, 256, 0, stream>>>(CFG1, CFG2, counts, edges);
  k_gru<<<64, 64, 0, stream>>>(xp, GRK1, GB1, GRK2, GB2, wh);
  for (int step = 0; step < 3; ++step) {
    k_whg<<<1024, 64, 0, stream>>>(wh, WG, A1W, A1B, A2W, A2B, whg, ah1, ah2);
    k_attn<<<16384, 256, 0, stream>>>(wh, whg, ah1, ah2, counts, edges);
  }
  k_tail<<<64, 256, 0, stream>>>(wh, WOUT, BOUT, e12);
  k_cos<<<1, 64, 0, stream>>>(e12, (float*)d_out);
}

// Round 5
// 778.073 us; speedup vs baseline: 1.1895x; 1.1895x over previous
//
#include <hip/hip_runtime.h>
#include <hip/hip_bf16.h>

// Problem constants
#define BB 32
#define NNODE 512
#define EE 128
#define MAXDEG 64  // fixed edge slots per row (binomial(512,.05) max ~53)

typedef float v2f __attribute__((ext_vector_type(2)));
typedef __fp16 h2 __attribute__((ext_vector_type(2)));  // matches cvt_pkrtz
__device__ __forceinline__ v2f fma2(v2f a, v2f b, v2f c) {
  return __builtin_elementwise_fma(a, b, c);
}

// Fast gates: v_rcp_f32 instead of full-precision divide (~1ulp).
__device__ __forceinline__ float sigm_fast(float x) {
  return __builtin_amdgcn_rcpf(1.0f + __expf(-x));
}
__device__ __forceinline__ float tanh_fast(float x) {
  x = fminf(20.f, fmaxf(-20.f, x));
  float t = __expf(-2.f * x);
  return (1.f - t) * __builtin_amdgcn_rcpf(1.f + t);
}

// ---------------------------------------------------------------------------
// wh[2s|2s+1][:, 0:64] = relu(LIT @ W_lit); xp = SEM @ gru_k + gru_b[0]
// grid 1024 x 64.
__global__ __launch_bounds__(64, 1) void k_data(
    const float* __restrict__ lit1, const float* __restrict__ sem1,
    const float* __restrict__ lit2, const float* __restrict__ sem2,
    const float* __restrict__ wl1, const float* __restrict__ gk1,
    const float* __restrict__ gb1, const float* __restrict__ wl2,
    const float* __restrict__ gk2, const float* __restrict__ gb2,
    float* __restrict__ wh, float* __restrict__ xp) {
  __shared__ float stage[64 * 65];
  int bid = blockIdx.x;
  int rowblk = bid >> 1, half = bid & 1;
  int grow0 = rowblk * 64;
  int side = grow0 >> 14;
  int lrow0 = grow0 & 16383;
  const float* lit = side ? lit2 : lit1;
  const float* sem = side ? sem2 : sem1;
  const float* wl = side ? wl2 : wl1;
  const float* gk = side ? gk2 : gk1;
  const float* gb = side ? gb2 : gb1;
  int tid = threadIdx.x;

  {
    const float4* lit4 = (const float4*)(lit + (size_t)lrow0 * 64);
#pragma unroll
    for (int p = 0; p < 16; ++p) {
      int s = p * 64 + tid;
      int r = s >> 4, q = s & 15;
      float4 v = lit4[r * 16 + q];
      stage[r * 65 + 4 * q + 0] = v.x;
      stage[r * 65 + 4 * q + 1] = v.y;
      stage[r * 65 + 4 * q + 2] = v.z;
      stage[r * 65 + 4 * q + 3] = v.w;
    }
    v2f acc[16];
#pragma unroll
    for (int c = 0; c < 16; ++c) acc[c] = (v2f){0.f, 0.f};
    const float4* wl4 = (const float4*)wl;  // [64][16] f4
    for (int i = 0; i < 64; ++i) {
      float rv = stage[tid * 65 + i];
      v2f rv2 = {rv, rv};
#pragma unroll
      for (int c4 = 0; c4 < 8; ++c4) {
        float4 w = wl4[i * 16 + half * 8 + c4];
        acc[2 * c4 + 0] = fma2(rv2, (v2f){w.x, w.y}, acc[2 * c4 + 0]);
        acc[2 * c4 + 1] = fma2(rv2, (v2f){w.z, w.w}, acc[2 * c4 + 1]);
      }
    }
    float4* w0 = (float4*)wh + ((size_t)(2 * side) * 16384 + lrow0 + tid) * 32;
    float4* w1 =
        (float4*)wh + ((size_t)(2 * side + 1) * 16384 + lrow0 + tid) * 32;
#pragma unroll
    for (int c4 = 0; c4 < 8; ++c4) {
      float4 o;
      o.x = fmaxf(acc[2 * c4].x, 0.f);
      o.y = fmaxf(acc[2 * c4].y, 0.f);
      o.z = fmaxf(acc[2 * c4 + 1].x, 0.f);
      o.w = fmaxf(acc[2 * c4 + 1].y, 0.f);
      w0[half * 8 + c4] = o;
      w1[half * 8 + c4] = o;
    }
  }
  {
    const float4* sem4 = (const float4*)(sem + (size_t)lrow0 * 64);
#pragma unroll
    for (int p = 0; p < 16; ++p) {
      int s = p * 64 + tid;
      int r = s >> 4, q = s & 15;
      float4 v = sem4[r * 16 + q];
      stage[r * 65 + 4 * q + 0] = v.x;
      stage[r * 65 + 4 * q + 1] = v.y;
      stage[r * 65 + 4 * q + 2] = v.z;
      stage[r * 65 + 4 * q + 3] = v.w;
    }
    v2f acc2[48];
#pragma unroll
    for (int c = 0; c < 48; ++c)
      acc2[c] = (v2f){gb[half * 96 + 2 * c], gb[half * 96 + 2 * c + 1]};
    const float4* gk4 = (const float4*)gk;  // [64][48] f4
    for (int i = 0; i < 64; ++i) {
      float rv = stage[tid * 65 + i];
      v2f rv2 = {rv, rv};
#pragma unroll
      for (int c4 = 0; c4 < 24; ++c4) {
        float4 w = gk4[i * 48 + half * 24 + c4];
        acc2[2 * c4 + 0] = fma2(rv2, (v2f){w.x, w.y}, acc2[2 * c4 + 0]);
        acc2[2 * c4 + 1] = fma2(rv2, (v2f){w.z, w.w}, acc2[2 * c4 + 1]);
      }
    }
    float4* xp4 = (float4*)xp;
    int grow = grow0 + tid;
#pragma unroll
    for (int c4 = 0; c4 < 24; ++c4) {
      float4 o;
      o.x = acc2[2 * c4].x;
      o.y = acc2[2 * c4].y;
      o.z = acc2[2 * c4 + 1].x;
      o.w = acc2[2 * c4 + 1].y;
      xp4[(size_t)grow * 48 + half * 24 + c4] = o;
    }
  }
}

// ---------------------------------------------------------------------------
// CSR/CSC build (standalone so the GRU kernel gets a full register budget).
// grid 1024 x 256.
__global__ __launch_bounds__(256, 1) void k_csr(
    const float* __restrict__ A1, const float* __restrict__ A2,
    int* __restrict__ counts, int* __restrict__ edges) {
  int bid = blockIdx.x;
  int t = threadIdx.x;
  if (bid < 512) {
    int s = bid >> 8, b = (bid >> 3) & 31, ch = bid & 7;
    const float* A = s ? A2 : A1;
    const float4* A4 = (const float4*)(A + ((size_t)b * 512 + ch * 64) * 512);
    __shared__ int crow[64];
    if (t < 64) crow[t] = 0;
    __syncthreads();
    int* efwd =
        edges + (size_t)(2 * s) * 1048576 + ((size_t)b * 512 + ch * 64) * 64;
#pragma unroll
    for (int it = 0; it < 32; ++it) {
      int idx = it * 256 + t;
      int r = idx >> 7, c4 = idx & 127;
      float4 v = A4[idx];
      float vv[4] = {v.x, v.y, v.z, v.w};
#pragma unroll
      for (int e = 0; e < 4; ++e) {
        if (vv[e] != 0.f) {
          int pos = atomicAdd(&crow[r], 1);
          if (pos < MAXDEG) efwd[r * 64 + pos] = 4 * c4 + e;
        }
      }
    }
    __syncthreads();
    if (t < 64)
      counts[(2 * s) * 16384 + b * 512 + ch * 64 + t] = min(crow[t], MAXDEG);
  } else {
    int bid2 = bid - 512;
    int s = bid2 >> 8, b = (bid2 >> 3) & 31, cch = bid2 & 7;
    const float* A = s ? A2 : A1;
    __shared__ int ccol[64];
    if (t < 64) ccol[t] = 0;
    __syncthreads();
    int lane = t & 63, rg = t >> 6;
    int c = cch * 64 + lane;
    int* erev = edges + (size_t)(2 * s + 1) * 1048576 + ((size_t)b * 512) * 64;
    const float* Ab = A + (size_t)b * 512 * 512;
    for (int it = 0; it < 128; ++it) {
      int r = it * 4 + rg;
      float a = Ab[(size_t)r * 512 + c];
      if (a != 0.f) {
        int pos = atomicAdd(&ccol[lane], 1);
        if (pos < MAXDEG) erev[(size_t)c * 64 + pos] = r;
      }
    }
    __syncthreads();
    if (t < 64)
      counts[(2 * s + 1) * 16384 + b * 512 + cch * 64 + t] =
          min(ccol[t], MAXDEG);
  }
}

// ---------------------------------------------------------------------------
// GRU scan, SINGLE-WAVE per sequence. f16 weight columns (96 half2 = 96
// VGPRs, was 192 f32) + f16 h-broadcast (8 ds_read_b128/step, was 16) +
// v_dot2_f32_f16 with fp32 accumulate. Total live pressure ~185 VGPRs ->
// fits without the scratch spill that made round 3's fp32 version 1470
// cy/step (VGPR_Count=140 = spilled weights).
// State, gates, outputs stay fp32; only matvec operands are f16.
// grid 64 x 64.
__global__ __launch_bounds__(64, 1) void k_gru(
    const float* __restrict__ xp, const float* __restrict__ rk1,
    const float* __restrict__ b1, const float* __restrict__ rk2,
    const float* __restrict__ b2, float* __restrict__ wh) {
  int blk = blockIdx.x;
  int side = blk >> 5, b = blk & 31;
  int jj = threadIdx.x;  // output index 0..63
  const float* rk = side ? rk2 : rk1;
  const float* bbp = side ? b2 : b1;
  // f16 weight column for this lane: pair k covers rows 2k,2k+1 of rk.
  // Split into A (k=0..15) and B (k=16..31) arrays: smaller allocas for SROA.
  h2 wzA[16], wzB[16], wrA[16], wrB[16], wvA[16], wvB[16];
#pragma unroll
  for (int k = 0; k < 16; ++k) {
    const float* r0 = rk + (size_t)(2 * k) * 192 + jj;
    const float* r1 = r0 + 192;
    wzA[k] = __builtin_amdgcn_cvt_pkrtz(r0[0], r1[0]);
    wrA[k] = __builtin_amdgcn_cvt_pkrtz(r0[64], r1[64]);
    wvA[k] = __builtin_amdgcn_cvt_pkrtz(r0[128], r1[128]);
  }
#pragma unroll
  for (int k = 0; k < 16; ++k) {
    const float* r0 = rk + (size_t)(2 * k + 32) * 192 + jj;
    const float* r1 = r0 + 192;
    wzB[k] = __builtin_amdgcn_cvt_pkrtz(r0[0], r1[0]);
    wrB[k] = __builtin_amdgcn_cvt_pkrtz(r0[64], r1[64]);
    wvB[k] = __builtin_amdgcn_cvt_pkrtz(r0[128], r1[128]);
  }
  float bz = bbp[192 + jj], brr = bbp[192 + 64 + jj], bv = bbp[192 + 128 + jj];

  __shared__ alignas(16) __fp16 hsh[64];
  hsh[jj] = (__fp16)0.f;
  float hold = 0.f;

  const float* xpr = xp + (size_t)(side * 16384 + b * 512) * 192;
  float* w0 = wh + ((size_t)(2 * side) * 16384 + b * 512) * 128 + 64 + jj;
  float* w1 = wh + ((size_t)(2 * side + 1) * 16384 + b * 512) * 128 + 64 + jj;

  float bufA[24], bufB[24];
  // load 8-step chunk tc into buf (per-lane scalars, coalesced 256B/instr)
  auto loadc = [&](float (&buf)[24], int tc) {
    const float* src = xpr + (size_t)tc * 8 * 192;
#pragma unroll
    for (int q = 0; q < 8; ++q) {
      buf[3 * q + 0] = src[q * 192 + jj];
      buf[3 * q + 1] = src[q * 192 + 64 + jj];
      buf[3 * q + 2] = src[q * 192 + 128 + jj];
    }
  };
  // one GRU step from buf[tt], global step index t
  auto gstep = [&](const float (&buf)[24], int tt, int t) {
    float cxz = buf[3 * tt + 0], cxr = buf[3 * tt + 1], cxv = buf[3 * tt + 2];
    const uint4* hb = (const uint4*)hsh;  // broadcast reads (conflict-free)
    float az0 = 0.f, az1 = 0.f, ar0 = 0.f, ar1 = 0.f, av0 = 0.f, av1 = 0.f;
#pragma unroll
    for (int c = 0; c < 8; ++c) {
      uint4 hv = hb[c];  // h halves 8c..8c+7 -> pairs k=4c..4c+3
      unsigned int hw[4] = {hv.x, hv.y, hv.z, hv.w};
#pragma unroll
      for (int i = 0; i < 4; ++i) {
        int k = 4 * c + i;
        h2 p = __builtin_bit_cast(h2, hw[i]);
        h2 wzk = k < 16 ? wzA[k] : wzB[k - 16];
        h2 wrk = k < 16 ? wrA[k] : wrB[k - 16];
        h2 wvk = k < 16 ? wvA[k] : wvB[k - 16];
        if (k & 1) {
          az1 = __builtin_amdgcn_fdot2(p, wzk, az1, false);
          ar1 = __builtin_amdgcn_fdot2(p, wrk, ar1, false);
          av1 = __builtin_amdgcn_fdot2(p, wvk, av1, false);
        } else {
          az0 = __builtin_amdgcn_fdot2(p, wzk, az0, false);
          ar0 = __builtin_amdgcn_fdot2(p, wrk, ar0, false);
          av0 = __builtin_amdgcn_fdot2(p, wvk, av0, false);
        }
      }
    }
    float saz = az0 + az1, sar = ar0 + ar1, sav = av0 + av1;
    float z = sigm_fast(cxz + saz + bz);
    float r = sigm_fast(cxr + sar + brr);
    float hh = tanh_fast(cxv + r * (sav + bv));
    float hnew = fmaf(z, hold - hh, hh);
    hold = hnew;
    // Pin schedule: all hsh reads of this step issue before the write below.
    __builtin_amdgcn_sched_barrier(0);
    hsh[jj] = (__fp16)hnew;
    float rv = fmaxf(hnew, 0.f);
    w0[(size_t)t * 128] = rv;
    w1[(size_t)t * 128] = rv;
  };

  loadc(bufA, 0);
  for (int tc2 = 0; tc2 < 32; ++tc2) {  // 64 chunks of 8 steps, paired A/B
    int tcA = 2 * tc2, tcB = 2 * tc2 + 1;
    loadc(bufB, tcB);  // prefetch while computing A
#pragma unroll
    for (int tt = 0; tt < 8; ++tt) gstep(bufA, tt, tcA * 8 + tt);
    if (tcB + 1 < 64) loadc(bufA, tcB + 1);  // prefetch while computing B
#pragma unroll
    for (int tt = 0; tt < 8; ++tt) gstep(bufB, tt, tcB * 8 + tt);
  }
}

// ---------------------------------------------------------------------------
// whg (PACKED BF16: uint = 2 cols) = wh @ W_g; ah1/ah2 fp32.
// grid 1024 x 64; one wave = 64 rows. XCD-swizzled (blockIdx%8 = XCD): all 8
// blocks of one (st,b) group land on the same XCD so whg stays in its L2.
__global__ __launch_bounds__(64, 1) void k_whg(
    const float* __restrict__ wh, const float* __restrict__ Wg,
    const float* __restrict__ a1w, const float* __restrict__ a1b,
    const float* __restrict__ a2w, const float* __restrict__ a2b,
    unsigned int* __restrict__ whg, float* __restrict__ ah1,
    float* __restrict__ ah2) {
  __shared__ float stage[64 * 129];
  int B = blockIdx.x;
  int xcd = B & 7, slot = B >> 3;   // slot 0..127
  int grp = xcd + 8 * (slot >> 3);  // (st,b) group 0..127
  int sub = slot & 7;               // 64-row tile within group
  int rowbase = grp * 512 + sub * 64;
  int tid = threadIdx.x;
  const float4* wh4 = (const float4*)(wh + (size_t)rowbase * 128);
#pragma unroll
  for (int p = 0; p < 32; ++p) {
    int s = p * 64 + tid;
    int r = s >> 5, q = s & 31;
    float4 v = wh4[r * 32 + q];
    stage[r * 129 + 4 * q + 0] = v.x;
    stage[r * 129 + 4 * q + 1] = v.y;
    stage[r * 129 + 4 * q + 2] = v.z;
    stage[r * 129 + 4 * q + 3] = v.w;
  }
  v2f acc[64];
#pragma unroll
  for (int c = 0; c < 64; ++c) acc[c] = (v2f){0.f, 0.f};
  float p1 = a1b[0], p2 = a2b[0];
  const float4* Wg4 = (const float4*)Wg;  // [128][32] f4
  for (int i = 0; i < 128; ++i) {
    float rv = stage[tid * 129 + i];
    v2f rv2 = {rv, rv};
    p1 = fmaf(rv, a1w[i], p1);
    p2 = fmaf(rv, a2w[i], p2);
#pragma unroll
    for (int c4 = 0; c4 < 32; ++c4) {
      float4 w = Wg4[i * 32 + c4];
      acc[2 * c4 + 0] = fma2(rv2, (v2f){w.x, w.y}, acc[2 * c4 + 0]);
      acc[2 * c4 + 1] = fma2(rv2, (v2f){w.z, w.w}, acc[2 * c4 + 1]);
    }
  }
  int grow = rowbase + tid;
  uint2* o2 = (uint2*)(whg + (size_t)grow * 64);
#pragma unroll
  for (int c4 = 0; c4 < 32; c4 += 2) {
    __hip_bfloat162 A =
        __float22bfloat162_rn(make_float2(acc[c4].x, acc[c4].y));
    __hip_bfloat162 Bv =
        __float22bfloat162_rn(make_float2(acc[c4 + 1].x, acc[c4 + 1].y));
    uint2 pk;
    pk.x = *(unsigned int*)&A;
    pk.y = *(unsigned int*)&Bv;
    o2[c4 >> 1] = pk;
  }
  ah1[grow] = p1;
  ah2[grow] = p2;
}

// ---------------------------------------------------------------------------
// Per-row edge softmax + aggregate + elu. One wave per row, 4 rows per block.
// Lane-parallel setup; shfl-broadcast gather; whg is PACKED BF16 so each lane
// reads ONE 4B uint (2 cols) per edge — half the loads/bytes of fp32.
// XCD-swizzled to match k_whg. grid 16384 x 256.
__global__ __launch_bounds__(256, 1) void k_attn(
    float* __restrict__ wh, const unsigned int* __restrict__ whg,
    const float* __restrict__ ah1, const float* __restrict__ ah2,
    const int* __restrict__ counts, const int* __restrict__ edges) {
  int B = blockIdx.x;
  int xcd = B & 7, slot = B >> 3;   // slot 0..2047
  int grp = xcd + 8 * (slot >> 7);  // group 0..127
  int sub = slot & 127;             // 0..127 (4 rows each)
  int row = grp * 512 + sub * 4 + (threadIdx.x >> 6);
  int lane = threadIdx.x & 63;
  int st = row >> 14;
  int loc = row & 16383;
  int base = row & ~511;
  int cnt = counts[row];
  const int* ed = edges + (size_t)st * 1048576 + (size_t)loc * 64;
  int jk = lane < cnt ? ed[lane] : 0;
  float a1v = ah1[row];
  float e = a1v + ah2[base + jk];
  e = e >= 0.f ? e : 0.2f * e;  // leaky_relu 0.2
  float w = lane < cnt ? __expf(e) : 0.f;
  float lsum = w;
#pragma unroll
  for (int off = 32; off; off >>= 1) lsum += __shfl_xor(lsum, off, 64);
  float inv = cnt > 0 ? 1.0f / lsum : 0.f;
  const unsigned int* wgb = whg + (size_t)base * 64;
  v2f a0 = {0.f, 0.f}, a1 = {0.f, 0.f}, a2 = {0.f, 0.f}, a3 = {0.f, 0.f};
  int k = 0;
  for (; k + 4 <= cnt; k += 4) {
    float w0 = __shfl(w, k, 64), w1 = __shfl(w, k + 1, 64);
    float w2 = __shfl(w, k + 2, 64), w3 = __shfl(w, k + 3, 64);
    int j0 = __shfl(jk, k, 64), j1 = __shfl(jk, k + 1, 64);
    int j2 = __shfl(jk, k + 2, 64), j3 = __shfl(jk, k + 3, 64);
    unsigned int d0 = wgb[(size_t)j0 * 64 + lane];
    unsigned int d1 = wgb[(size_t)j1 * 64 + lane];
    unsigned int d2 = wgb[(size_t)j2 * 64 + lane];
    unsigned int d3 = wgb[(size_t)j3 * 64 + lane];
    v2f v0 = {__uint_as_float(d0 << 16), __uint_as_float(d0 & 0xffff0000u)};
    v2f v1 = {__uint_as_float(d1 << 16), __uint_as_float(d1 & 0xffff0000u)};
    v2f v2 = {__uint_as_float(d2 << 16), __uint_as_float(d2 & 0xffff0000u)};
    v2f v3 = {__uint_as_float(d3 << 16), __uint_as_float(d3 & 0xffff0000u)};
    a0 = fma2((v2f){w0, w0}, v0, a0);
    a1 = fma2((v2f){w1, w1}, v1, a1);
    a2 = fma2((v2f){w2, w2}, v2, a2);
    a3 = fma2((v2f){w3, w3}, v3, a3);
  }
  for (; k < cnt; ++k) {
    float w0 = __shfl(w, k, 64);
    int j0 = __shfl(jk, k, 64);
    unsigned int d0 = wgb[(size_t)j0 * 64 + lane];
    v2f v0 = {__uint_as_float(d0 << 16), __uint_as_float(d0 & 0xffff0000u)};
    a0 = fma2((v2f){w0, w0}, v0, a0);
  }
  v2f acc = (a0 + a1) + (a2 + a3);
  // lane covers cols 2*lane, 2*lane+1
  float2* wr2 = (float2*)(wh + (size_t)row * 128);
  float2 old = wr2[lane];
  float o0 = old.x + acc.x * inv;
  float o1 = old.y + acc.y * inv;
  o0 = o0 > 0.f ? o0 : __expf(o0) - 1.f;  // elu
  o1 = o1 > 0.f ? o1 : __expf(o1) - 1.f;
  wr2[lane] = make_float2(o0, o1);
}

// ---------------------------------------------------------------------------
// Fused node-sum + output projection. grid 64 x 256. Block = (side,b).
__global__ __launch_bounds__(256, 1) void k_tail(const float* __restrict__ wh,
                                                 const float* __restrict__ Wout,
                                                 const float* __restrict__ bout,
                                                 float* __restrict__ e12) {
  int sb = blockIdx.x;
  int side = sb >> 5, b = sb & 31;
  int t = threadIdx.x;
  int c = t & 127, half = t >> 7;
  __shared__ float part[2][128];
  __shared__ float mid[128];
  size_t s0 = ((size_t)(2 * side) * 16384 + b * 512) * 128;
  size_t s1 = ((size_t)(2 * side + 1) * 16384 + b * 512) * 128;
  float sum = 0.f;
  int r0 = half * 256;
  for (int r = r0; r < r0 + 256; ++r) {
    sum += wh[s0 + (size_t)r * 128 + c] + wh[s1 + (size_t)r * 128 + c];
  }
  part[half][c] = sum;
  __syncthreads();
  if (t < 128) mid[t] = part[0][t] + part[1][t];
  __syncthreads();
  if (t < 64) {
    float acc = bout[t];
    for (int k2 = 0; k2 < 128; ++k2) acc = fmaf(mid[k2], Wout[k2 * 64 + t], acc);
    e12[sb * 64 + t] = acc;
  }
}

__global__ void k_cos(const float* __restrict__ e12, float* __restrict__ out) {
  int b = threadIdx.x;
  if (b >= 32) return;
  const float* e1 = e12 + b * 64;
  const float* e2 = e12 + 2048 + b * 64;
  float d = 0.f, n1 = 0.f, n2 = 0.f;
  for (int o = 0; o < 64; ++o) {
    float a = e1[o], c = e2[o];
    d = fmaf(a, c, d);
    n1 = fmaf(a, a, n1);
    n2 = fmaf(c, c, n2);
  }
  float nn = fmaxf(sqrtf(n1), 1e-12f) * fmaxf(sqrtf(n2), 1e-12f);
  out[b] = 0.5f * (1.f + d / nn);
}

// ---------------------------------------------------------------------------
extern "C" void kernel_launch(void* const* d_in, const int* in_sizes, int n_in,
                              void* d_out, int out_size, void* d_ws,
                              size_t ws_size, hipStream_t stream) {
  const float* CFG1 = (const float*)d_in[0];
  const float* LIT1 = (const float*)d_in[2];
  const float* SEM1 = (const float*)d_in[3];
  const float* CFG2 = (const float*)d_in[4];
  const float* LIT2 = (const float*)d_in[6];
  const float* SEM2 = (const float*)d_in[7];
  const float* WL1 = (const float*)d_in[8];
  const float* GK1 = (const float*)d_in[9];
  const float* GRK1 = (const float*)d_in[10];
  const float* GB1 = (const float*)d_in[11];
  const float* WL2 = (const float*)d_in[12];
  const float* GK2 = (const float*)d_in[13];
  const float* GRK2 = (const float*)d_in[14];
  const float* GB2 = (const float*)d_in[15];
  const float* A1W = (const float*)d_in[16];
  const float* A1B = (const float*)d_in[17];
  const float* A2W = (const float*)d_in[18];
  const float* A2B = (const float*)d_in[19];
  const float* WG = (const float*)d_in[20];
  const float* WOUT = (const float*)d_in[21];
  const float* BOUT = (const float*)d_in[22];

  float* ws = (float*)d_ws;
  float* wh = ws;            // 8388608 floats
  float* xp = wh + 8388608;  // 6291456
  unsigned int* whg = (unsigned int*)(xp + 6291456);  // 4194304 uints
  float* ah1 = (float*)(whg + 4194304);               // 65536
  float* ah2 = ah1 + 65536;                           // 65536
  float* e12 = ah2 + 65536;                           // 4096
  int* counts = (int*)(e12 + 4096);                   // 65536
  int* edges = counts + 65536;  // 4*16384*64 = 4194304

  k_data<<<1024, 64, 0, stream>>>(LIT1, SEM1, LIT2, SEM2, WL1, GK1, GB1, WL2,
                                  GK2, GB2, wh, xp);
  k_csr<<<1024, 256, 0, stream>>>(CFG1, CFG2, counts, edges);
  k_gru<<<64, 64, 0, stream>>>(xp, GRK1, GB1, GRK2, GB2, wh);
  for (int step = 0; step < 3; ++step) {
    k_whg<<<1024, 64, 0, stream>>>(wh, WG, A1W, A1B, A2W, A2B, whg, ah1, ah2);
    k_attn<<<16384, 256, 0, stream>>>(wh, whg, ah1, ah2, counts, edges);
  }
  k_tail<<<64, 256, 0, stream>>>(wh, WOUT, BOUT, e12);
  k_cos<<<1, 64, 0, stream>>>(e12, (float*)d_out);
}